// Round 1
// baseline (106.805 us; speedup 1.0000x reference)
//
#include <hip/hip_runtime.h>

// 3D median filter 3x3x3, zero padding, exact median of 27.
// Strategy: sort window along z, then y, then x (all lines sorted afterwards,
// by the classic shearsort lemma). Dominance-prune 8 elements that provably
// cannot be the median (4 below, 4 above), then forgetful selection on the
// remaining 19 candidates (working set 11). Verified exact via 0-1 principle.

#define CE(a, b)                      \
    do {                              \
        float _t = fminf((a), (b));   \
        (b) = fmaxf((a), (b));        \
        (a) = _t;                     \
    } while (0)

__device__ __forceinline__ void sort3(float &a, float &b, float &c) {
    float lo = fminf(fminf(a, b), c);          // v_min3_f32
    float hi = fmaxf(fmaxf(a, b), c);          // v_max3_f32
    float md = __builtin_amdgcn_fmed3f(a, b, c); // v_med3_f32
    a = lo; b = md; c = hi;
}

// Places min of v[LO..HI] at v[LO] and max at v[HI]; multiset preserved.
// Window size (HI-LO+1) must be odd. Cost: (3s-3)/2 compare-exchanges.
template <int LO, int HI>
__device__ __forceinline__ void minmax_round(float *v) {
#pragma unroll
    for (int i = LO + 1; i < HI; i += 2) CE(v[i], v[i + 1]);
    CE(v[LO], v[LO + 1]);
#pragma unroll
    for (int i = LO + 3; i < HI; i += 2) CE(v[LO], v[i]);   // min funnel
#pragma unroll
    for (int i = LO + 2; i < HI; i += 2) CE(v[i], v[HI]);   // max funnel
    CE(v[LO + 1], v[HI]);
}

__global__ __launch_bounds__(256) void median3d_kernel(
    const float *__restrict__ x, float *__restrict__ out) {
    const int W = 256, H = 256, D = 64;
    const int w = blockIdx.x * blockDim.x + threadIdx.x;
    const int h = blockIdx.y * blockDim.y + threadIdx.y;
    const int d = blockIdx.z;

    float v[27];
#pragma unroll
    for (int dz = 0; dz < 3; ++dz) {
#pragma unroll
        for (int dy = 0; dy < 3; ++dy) {
#pragma unroll
            for (int dx = 0; dx < 3; ++dx) {
                const int dd = d + dz - 1;
                const int hh = h + dy - 1;
                const int ww = w + dx - 1;
                const bool ok = ((unsigned)dd < (unsigned)D) &&
                                ((unsigned)hh < (unsigned)H) &&
                                ((unsigned)ww < (unsigned)W);
                v[dz * 9 + dy * 3 + dx] =
                    ok ? x[(dd * H + hh) * W + ww] : 0.0f;
            }
        }
    }

    // Sort along z (9 lines), then y (9), then x (9).
#pragma unroll
    for (int o = 0; o < 9; ++o) sort3(v[o], v[9 + o], v[18 + o]);
#pragma unroll
    for (int z = 0; z < 3; ++z) {
#pragma unroll
        for (int xx = 0; xx < 3; ++xx)
            sort3(v[9 * z + xx], v[9 * z + 3 + xx], v[9 * z + 6 + xx]);
    }
#pragma unroll
    for (int z = 0; z < 3; ++z) {
#pragma unroll
        for (int y = 0; y < 3; ++y)
            sort3(v[9 * z + 3 * y], v[9 * z + 3 * y + 1], v[9 * z + 3 * y + 2]);
    }

    // Candidates: all flat indices except low-dropped {0,1,3,9} and
    // high-dropped {17,23,25,26}.
    const int cidx[19] = {2,  4,  5,  6,  7,  8,  10, 11, 12, 13,
                          14, 15, 16, 18, 19, 20, 21, 22, 24};
    float wk[11];
#pragma unroll
    for (int i = 0; i < 11; ++i) wk[i] = v[cidx[i]];

    minmax_round<0, 10>(wk); wk[0] = v[cidx[11]]; wk[10] = v[cidx[12]];
    minmax_round<0, 10>(wk); wk[0] = v[cidx[13]]; wk[10] = v[cidx[14]];
    minmax_round<0, 10>(wk); wk[0] = v[cidx[15]]; wk[10] = v[cidx[16]];
    minmax_round<0, 10>(wk); wk[0] = v[cidx[17]]; wk[10] = v[cidx[18]];
    // Median of 19 now = median of wk[0..10]. Shrink.
    minmax_round<0, 10>(wk);
    minmax_round<1, 9>(wk);
    minmax_round<2, 8>(wk);
    minmax_round<3, 7>(wk);

    out[(d * H + h) * W + w] = __builtin_amdgcn_fmed3f(wk[4], wk[5], wk[6]);
}

extern "C" void kernel_launch(void *const *d_in, const int *in_sizes, int n_in,
                              void *d_out, int out_size, void *d_ws,
                              size_t ws_size, hipStream_t stream) {
    const float *x = (const float *)d_in[0];
    float *out = (float *)d_out;
    dim3 block(64, 4, 1);
    dim3 grid(256 / 64, 256 / 4, 64);
    median3d_kernel<<<grid, block, 0, stream>>>(x, out);
}

// Round 2
// 93.083 us; speedup vs baseline: 1.1474x; 1.1474x over previous
//
#include <hip/hip_runtime.h>

// 3D median 3x3x3, zero pad, exact. Round 2: 4-output x-strip per thread.
// - 9 coalesced float4 loads/thread; halo via __shfl from neighbor lanes
//   (wave = full 256-wide row, so wave edge == image edge).
// - z-sort + y-sort shared across the 4 outputs (6-wide column array).
// - Per output: pruned x-sort (19 of 27 line stats) + forgetful selection.
// Monotone-cube pruning validity: z,y sorts on 6-wide array restricted to any
// 3 columns + x-sort == full 3D shear sort (sorting rows after columns keeps
// columns sorted; sorting preserves elementwise slice dominance). Exactness
// verified round 1 (absmax 0.0).

#define CE(a, b)                      \
    do {                              \
        float _t = fminf((a), (b));   \
        (b) = fmaxf((a), (b));        \
        (a) = _t;                     \
    } while (0)

__device__ __forceinline__ float min3f(float a, float b, float c) {
    return fminf(fminf(a, b), c);
}
__device__ __forceinline__ float max3f(float a, float b, float c) {
    return fmaxf(fmaxf(a, b), c);
}
__device__ __forceinline__ float med3f(float a, float b, float c) {
    return __builtin_amdgcn_fmed3f(a, b, c);
}
__device__ __forceinline__ void sort3(float &a, float &b, float &c) {
    float lo = min3f(a, b, c);
    float hi = max3f(a, b, c);
    float md = med3f(a, b, c);
    a = lo; b = md; c = hi;
}

// min of v[LO..HI] -> v[LO], max -> v[HI]; multiset preserved. Odd size.
template <int LO, int HI>
__device__ __forceinline__ void minmax_round(float *v) {
#pragma unroll
    for (int i = LO + 1; i < HI; i += 2) CE(v[i], v[i + 1]);
    CE(v[LO], v[LO + 1]);
#pragma unroll
    for (int i = LO + 3; i < HI; i += 2) CE(v[LO], v[i]);
#pragma unroll
    for (int i = LO + 2; i < HI; i += 2) CE(v[i], v[HI]);
    CE(v[LO + 1], v[HI]);
}

__global__ __launch_bounds__(256) void median3d_kernel(
    const float *__restrict__ x, float *__restrict__ out) {
    const int W = 256, H = 256, D = 64;
    const int lane = threadIdx.x;      // 0..63, wave spans the full x row
    const int w0 = lane << 2;          // 4 outputs: w0..w0+3
    const int h = blockIdx.y * 4 + threadIdx.y;
    const int d = blockIdx.z;

    // v[(z*3+y)*6 + xi], xi=0 <-> x=w0-1 ... xi=5 <-> x=w0+4
    float v[54];
#pragma unroll
    for (int dz = 0; dz < 3; ++dz) {
        const int dd = d + dz - 1;
        const bool zok = (unsigned)dd < (unsigned)D;
        const int dc = zok ? dd : 0;
#pragma unroll
        for (int dy = 0; dy < 3; ++dy) {
            const int hh = h + dy - 1;
            const bool ok = zok && ((unsigned)hh < (unsigned)H);
            const int hc = ((unsigned)hh < (unsigned)H) ? hh : 0;
            const float4 ld =
                *(const float4 *)(x + ((size_t)(dc * H + hc)) * W + w0);
            float cx = ok ? ld.x : 0.0f;
            float cy = ok ? ld.y : 0.0f;
            float cz = ok ? ld.z : 0.0f;
            float cw = ok ? ld.w : 0.0f;
            // halo from neighbor lanes (wave-uniform ok => zeros propagate)
            float l = __shfl_up(cw, 1);
            float r = __shfl_down(cx, 1);
            l = (lane == 0) ? 0.0f : l;
            r = (lane == 63) ? 0.0f : r;
            const int base = (dz * 3 + dy) * 6;
            v[base + 0] = l;  v[base + 1] = cx; v[base + 2] = cy;
            v[base + 3] = cz; v[base + 4] = cw; v[base + 5] = r;
        }
    }

    // Shared z-sort then y-sort over all 6 columns.
#pragma unroll
    for (int y = 0; y < 3; ++y)
#pragma unroll
        for (int xi = 0; xi < 6; ++xi)
            sort3(v[(0 * 3 + y) * 6 + xi], v[(1 * 3 + y) * 6 + xi],
                  v[(2 * 3 + y) * 6 + xi]);
#pragma unroll
    for (int z = 0; z < 3; ++z)
#pragma unroll
        for (int xi = 0; xi < 6; ++xi)
            sort3(v[(z * 3 + 0) * 6 + xi], v[(z * 3 + 1) * 6 + xi],
                  v[(z * 3 + 2) * 6 + xi]);

    float res[4];
#pragma unroll
    for (int o = 0; o < 4; ++o) {
        // Pruned x-sort: lines L=(z*3+y), cols o..o+2. Keep 19 candidates
        // (drop flat {0,1,3,9} low and {17,23,25,26} high).
        float cand[19];
        {
            const float *p;
            p = &v[0 * 6 + o];  // (z0,y0): flat 2 = max
            cand[0] = max3f(p[0], p[1], p[2]);
            p = &v[1 * 6 + o];  // (z0,y1): flat 4,5 = med,max
            cand[1] = med3f(p[0], p[1], p[2]);
            cand[2] = max3f(p[0], p[1], p[2]);
            p = &v[2 * 6 + o];  // (z0,y2): flat 6,7,8
            { float a = p[0], b = p[1], c = p[2]; sort3(a, b, c);
              cand[3] = a; cand[4] = b; cand[5] = c; }
            p = &v[3 * 6 + o];  // (z1,y0): flat 10,11 = med,max
            cand[6] = med3f(p[0], p[1], p[2]);
            cand[7] = max3f(p[0], p[1], p[2]);
            p = &v[4 * 6 + o];  // (z1,y1): flat 12,13,14
            { float a = p[0], b = p[1], c = p[2]; sort3(a, b, c);
              cand[8] = a; cand[9] = b; cand[10] = c; }
            p = &v[5 * 6 + o];  // (z1,y2): flat 15,16 = min,med
            cand[11] = min3f(p[0], p[1], p[2]);
            cand[12] = med3f(p[0], p[1], p[2]);
            p = &v[6 * 6 + o];  // (z2,y0): flat 18,19,20
            { float a = p[0], b = p[1], c = p[2]; sort3(a, b, c);
              cand[13] = a; cand[14] = b; cand[15] = c; }
            p = &v[7 * 6 + o];  // (z2,y1): flat 21,22 = min,med
            cand[16] = min3f(p[0], p[1], p[2]);
            cand[17] = med3f(p[0], p[1], p[2]);
            p = &v[8 * 6 + o];  // (z2,y2): flat 24 = min
            cand[18] = min3f(p[0], p[1], p[2]);
        }
        // Forgetful selection: 10th smallest of 19 (window 11). Any feed
        // order is exact (dropped min rank <= 9, dropped max rank >= 11).
        float wk[11];
#pragma unroll
        for (int i = 0; i < 11; ++i) wk[i] = cand[i];
        minmax_round<0, 10>(wk); wk[0] = cand[11]; wk[10] = cand[12];
        minmax_round<0, 10>(wk); wk[0] = cand[13]; wk[10] = cand[14];
        minmax_round<0, 10>(wk); wk[0] = cand[15]; wk[10] = cand[16];
        minmax_round<0, 10>(wk); wk[0] = cand[17]; wk[10] = cand[18];
        minmax_round<0, 10>(wk);
        minmax_round<1, 9>(wk);
        minmax_round<2, 8>(wk);
        minmax_round<3, 7>(wk);
        res[o] = med3f(wk[4], wk[5], wk[6]);
    }

    float4 r4 = make_float4(res[0], res[1], res[2], res[3]);
    *(float4 *)(out + ((size_t)(d * H + h)) * W + w0) = r4;
}

extern "C" void kernel_launch(void *const *d_in, const int *in_sizes, int n_in,
                              void *d_out, int out_size, void *d_ws,
                              size_t ws_size, hipStream_t stream) {
    const float *x = (const float *)d_in[0];
    float *out = (float *)d_out;
    dim3 block(64, 4, 1);
    dim3 grid(1, 256 / 4, 64);
    median3d_kernel<<<grid, block, 0, stream>>>(x, out);
}

// Round 3
// 89.932 us; speedup vs baseline: 1.1876x; 1.0350x over previous
//
#include <hip/hip_runtime.h>

// 3D median 3x3x3, zero pad, exact. Round 3:
// - Halo via 2 extra clamped scalar loads per row (no __shfl / LDS pipe).
// - Poset-aware selection: after z,y,x shear sort the cube is monotone in all
//   axes. 4x sort3 on antichain triples excludes 2 low + 2 high candidates
//   (rank-counting certificates: min of {(0,1,1),(1,0,1),(1,1,0)} has >=16 of
//   19 elements >= it; min of {(0,0,2),(0,2,0),(2,0,0)} has >=15; maxes of
//   {(1,1,2),(1,2,1),(2,1,1)} / {(0,2,2),(2,0,2),(2,2,0)} symmetric). Then
//   rank-8-of-15 forgetful with window 9 (sound: 9 >= max(8,15-8)+1), with a
//   specialized first round (window min in {p2,r2}, max in {r3,q2,s2} by
//   in-window chain relations p2<=p3<=111<=q1<=q2, r2<=r3, r2<=s1<=s2).
// Exactness of shear-sort + prune verified rounds 1-2 (absmax 0.0).

#define CE(a, b)                      \
    do {                              \
        float _t = fminf((a), (b));   \
        (b) = fmaxf((a), (b));        \
        (a) = _t;                     \
    } while (0)

__device__ __forceinline__ float min3f(float a, float b, float c) {
    return fminf(fminf(a, b), c);
}
__device__ __forceinline__ float max3f(float a, float b, float c) {
    return fmaxf(fmaxf(a, b), c);
}
__device__ __forceinline__ float med3f(float a, float b, float c) {
    return __builtin_amdgcn_fmed3f(a, b, c);
}
__device__ __forceinline__ void sort3(float &a, float &b, float &c) {
    float lo = min3f(a, b, c);
    float hi = max3f(a, b, c);
    float md = med3f(a, b, c);
    a = lo; b = md; c = hi;
}

// min of v[LO..HI] -> v[LO], max -> v[HI]; multiset preserved. Odd size.
template <int LO, int HI>
__device__ __forceinline__ void minmax_round(float *v) {
#pragma unroll
    for (int i = LO + 1; i < HI; i += 2) CE(v[i], v[i + 1]);
    CE(v[LO], v[LO + 1]);
#pragma unroll
    for (int i = LO + 3; i < HI; i += 2) CE(v[LO], v[i]);
#pragma unroll
    for (int i = LO + 2; i < HI; i += 2) CE(v[i], v[HI]);
    CE(v[LO + 1], v[HI]);
}

__global__ __launch_bounds__(256) void median3d_kernel(
    const float *__restrict__ x, float *__restrict__ out) {
    const int W = 256, H = 256, D = 64;
    const int lane = threadIdx.x;   // 0..63, wave spans full x row
    const int w0 = lane << 2;       // 4 outputs: w0..w0+3
    const int h = blockIdx.y * 4 + threadIdx.y;
    const int d = blockIdx.z;
    // Clamped halo indices: keeps addresses in-bounds; value is cndmask'd to
    // zero at image edges anyway.
    const int wl = (lane == 0) ? 0 : (w0 - 1);
    const int wr = (lane == 63) ? (W - 1) : (w0 + 4);
    const bool lval = (lane != 0), rval = (lane != 63);

    // v[(z*3+y)*6 + xi], xi=0 <-> x=w0-1 ... xi=5 <-> x=w0+4
    float v[54];
#pragma unroll
    for (int dz = 0; dz < 3; ++dz) {
        const int dd = d + dz - 1;
        const bool zok = (unsigned)dd < (unsigned)D;
        const int dc = zok ? dd : 0;
#pragma unroll
        for (int dy = 0; dy < 3; ++dy) {
            const int hh = h + dy - 1;
            const bool hok = (unsigned)hh < (unsigned)H;
            const int hc = hok ? hh : 0;
            const bool ok = (dz == 1 && dy == 1) ? true : (zok && hok);
            const float *rowp = x + (size_t)(dc * H + hc) * W;
            float l = rowp[wl];
            float4 m = *(const float4 *)(rowp + w0);
            float r = rowp[wr];
            const int base = (dz * 3 + dy) * 6;
            v[base + 0] = (ok && lval) ? l : 0.0f;
            v[base + 1] = ok ? m.x : 0.0f;
            v[base + 2] = ok ? m.y : 0.0f;
            v[base + 3] = ok ? m.z : 0.0f;
            v[base + 4] = ok ? m.w : 0.0f;
            v[base + 5] = (ok && rval) ? r : 0.0f;
        }
    }

    // Shared z-sort then y-sort over all 6 columns.
#pragma unroll
    for (int y = 0; y < 3; ++y)
#pragma unroll
        for (int xi = 0; xi < 6; ++xi)
            sort3(v[(0 * 3 + y) * 6 + xi], v[(1 * 3 + y) * 6 + xi],
                  v[(2 * 3 + y) * 6 + xi]);
#pragma unroll
    for (int z = 0; z < 3; ++z)
#pragma unroll
        for (int xi = 0; xi < 6; ++xi)
            sort3(v[(z * 3 + 0) * 6 + xi], v[(z * 3 + 1) * 6 + xi],
                  v[(z * 3 + 2) * 6 + xi]);

    float res[4];
#pragma unroll
    for (int o = 0; o < 4; ++o) {
        // Band stats per line (z,y), sorted cube coords (z,y,0/1/2):
        const float *p;
        p = &v[0 * 6 + o];                    // line (0,0): need max
        float A02 = max3f(p[0], p[1], p[2]);
        p = &v[1 * 6 + o];                    // (0,1): med,max
        float A11 = med3f(p[0], p[1], p[2]);
        float A12 = max3f(p[0], p[1], p[2]);
        p = &v[2 * 6 + o];                    // (0,2): all
        float A20 = p[0], A21 = p[1], A22 = p[2]; sort3(A20, A21, A22);
        p = &v[3 * 6 + o];                    // (1,0): med,max
        float B01 = med3f(p[0], p[1], p[2]);
        float B02 = max3f(p[0], p[1], p[2]);
        p = &v[4 * 6 + o];                    // (1,1): all
        float B10 = p[0], B11 = p[1], B12 = p[2]; sort3(B10, B11, B12);
        p = &v[5 * 6 + o];                    // (1,2): min,med
        float B20 = min3f(p[0], p[1], p[2]);
        float B21 = med3f(p[0], p[1], p[2]);
        p = &v[6 * 6 + o];                    // (2,0): all
        float C00 = p[0], C01 = p[1], C02 = p[2]; sort3(C00, C01, C02);
        p = &v[7 * 6 + o];                    // (2,1): min,med
        float C10 = min3f(p[0], p[1], p[2]);
        float C11 = med3f(p[0], p[1], p[2]);
        p = &v[8 * 6 + o];                    // (2,2): min
        float C20 = min3f(p[0], p[1], p[2]);

        // Poset pre-exclusions (certificates in header comment):
        float pa = A11, pb = B01, pc = B10; sort3(pa, pb, pc);  // pa: <= med
        float qa = B12, qb = B21, qc = C11; sort3(qa, qb, qc);  // qc: >= med
        float ra = A02, rb = A20, rc = C00; sort3(ra, rb, rc);  // ra: <= med
        float sa = A22, sb = C02, sc = C20; sort3(sa, sb, sc);  // sc: >= med
        // Specialized round 1 on window {pb,pc,B11,qa,qb,rb,rc,sa,sb}:
        CE(pb, rb);              // pb = window min -> discard
        CE(rc, qb); CE(qb, sb);  // sb = window max -> discard
        // Remaining: rank 8 of 15. Window-9 forgetful.
        float wk[9] = {rb, pc, B11, qa, rc, qb, sa, A12, C10};
        minmax_round<0, 8>(wk); wk[0] = A21; wk[8] = C01;
        minmax_round<0, 8>(wk); wk[0] = B02; wk[8] = B20;
        minmax_round<0, 8>(wk);
        minmax_round<1, 7>(wk);
        minmax_round<2, 6>(wk);
        res[o] = med3f(wk[3], wk[4], wk[5]);
    }

    float4 r4 = make_float4(res[0], res[1], res[2], res[3]);
    *(float4 *)(out + ((size_t)(d * H + h)) * W + w0) = r4;
}

extern "C" void kernel_launch(void *const *d_in, const int *in_sizes, int n_in,
                              void *d_out, int out_size, void *d_ws,
                              size_t ws_size, hipStream_t stream) {
    const float *x = (const float *)d_in[0];
    float *out = (float *)d_out;
    dim3 block(64, 4, 1);
    dim3 grid(1, 256 / 4, 64);
    median3d_kernel<<<grid, block, 0, stream>>>(x, out);
}